// Round 20
// baseline (163.515 us; speedup 1.0000x reference)
//
#include <hip/hip_runtime.h>
#include <hip/hip_bf16.h>

#define GRID  32
#define NCELL (GRID * GRID * GRID)
#define H     0.3125f
#define INVH  3.2f
#define OFF   5.0f
#define SUBW  16
#define QPW   (64 / SUBW)
#define XPAD  136
#define NREP  16

using f32x4  = __attribute__((ext_vector_type(4))) float;
using bf16x8 = __attribute__((ext_vector_type(8))) short;

static __device__ inline short f2bs(float f) {
  __hip_bfloat16 h = __float2bfloat16(f);
  return __builtin_bit_cast(short, h);
}
static __device__ inline float bs2f(short s) {
  return __bfloat162float(__builtin_bit_cast(__hip_bfloat16, s));
}
static __device__ inline int cellco(float x) {
  int c = (int)((x + OFF) * INVH);
  return min(GRID - 1, max(0, c));
}

// branchless sorted-insert into named top-3 set
#define INS3(B0, B1, B2, J0, J1, J2, dv, mv)           \
  {                                                    \
    bool q0 = dv < B0, q1 = dv < B1, q2 = dv < B2;     \
    float P0 = B0, P1 = B1; int Q0 = J0, Q1 = J1;      \
    B2 = q1 ? P1 : (q2 ? dv : B2);                     \
    J2 = q1 ? Q1 : (q2 ? mv : J2);                     \
    B1 = q0 ? P0 : (q1 ? dv : P1);                     \
    J1 = q0 ? Q0 : (q1 ? mv : Q1);                     \
    B0 = q0 ? dv : P0;                                 \
    J0 = q0 ? mv : Q0;                                 \
  }
#define INSF(dv, mv) INS3(b0, b1, b2, j0, j1, j2, dv, mv)

#define MERGE3(lo_mk, hi_mk)                                                        \
  for (int mk = lo_mk; mk <= hi_mk; mk <<= 1) {                                     \
    float ob0 = __shfl_xor(b0, mk), ob1 = __shfl_xor(b1, mk), ob2 = __shfl_xor(b2, mk); \
    int   oj0 = __shfl_xor(j0, mk), oj1 = __shfl_xor(j1, mk), oj2 = __shfl_xor(j2, mk); \
    INSF(ob0, oj0); INSF(ob1, oj1); INSF(ob2, oj2);                                 \
  }

// ---- fast workspace zeroing ----
__global__ __launch_bounds__(256) void zero_k(int4* __restrict__ dst, int n4) {
  int i = blockIdx.x * 256 + threadIdx.x;
  if (i < n4) dst[i] = int4{0, 0, 0, 0};
}

// ---- histogram knowns + queries into cells; convert W to bf16 ----
__global__ __launch_bounds__(256) void hist_k(
    const float* __restrict__ known, int Mtot, int Mi,
    const float* __restrict__ unknown, int Ntot,
    int* __restrict__ khist, int* __restrict__ qhist,
    int* __restrict__ kcell, int* __restrict__ qcell,
    const float* __restrict__ W1, const float* __restrict__ W2,
    __hip_bfloat16* __restrict__ Wb1, __hip_bfloat16* __restrict__ Wb2) {
  int i = blockIdx.x * 256 + threadIdx.x;
  if (i < 128 * 128) {
    Wb1[i] = __float2bfloat16(W1[i]);
    Wb2[i] = __float2bfloat16(W2[i]);
  }
  if (i < Mtot) {
    int b = i / Mi;
    float x = known[(size_t)i * 3], y = known[(size_t)i * 3 + 1], z = known[(size_t)i * 3 + 2];
    int c = b * NCELL + (cellco(z) * GRID + cellco(y)) * GRID + cellco(x);
    kcell[i] = c;
    atomicAdd(&khist[c], 1);
  }
  if (i < Ntot) {
    int Ni = Ntot / (Mtot / Mi);
    int b = i / Ni;
    float x = unknown[(size_t)i * 3], y = unknown[(size_t)i * 3 + 1], z = unknown[(size_t)i * 3 + 2];
    int c = b * NCELL + (cellco(z) * GRID + cellco(y)) * GRID + cellco(x);
    qcell[i] = c;
    atomicAdd(&qhist[c], 1);
  }
}

// ---- scan1: per-block sums of combined [khist|qhist] ----
__global__ __launch_bounds__(256) void scan1_k(
    const int4* __restrict__ Hc4, int* __restrict__ bsum) {
  __shared__ int sh[256];
  int t = threadIdx.x;
  int4 h = Hc4[blockIdx.x * 256 + t];
  int s = h.x + h.y + h.z + h.w;
  sh[t] = s;
  __syncthreads();
  for (int d = 128; d > 0; d >>= 1) {
    if (t < d) sh[t] += sh[t + d];
    __syncthreads();
  }
  if (t == 0) bsum[blockIdx.x] = sh[0];
}

// ---- scan3: redundant bsum scan + local rescan + write start/fill ----
__global__ __launch_bounds__(256) void scan3_k(
    const int4* __restrict__ Hc4, const int* __restrict__ bsum, int nbk,
    int* __restrict__ kstart, int* __restrict__ kfill,
    int* __restrict__ qstart, int* __restrict__ qfill,
    int nc, int Mtot, int Ntot) {
  __shared__ int sh[256];
  __shared__ int sv[256], sc[256];
  int t = threadIdx.x;
  int v = (t < nbk) ? bsum[t] : 0;
  sv[t] = v; sc[t] = v;
  int g4 = blockIdx.x * 256 + t;
  int4 h = Hc4[g4];
  int s = h.x + h.y + h.z + h.w;
  sh[t] = s;
  __syncthreads();
  for (int d = 1; d < 256; d <<= 1) {
    int u1 = (t >= d) ? sc[t - d] : 0;
    int u2 = (t >= d) ? sh[t - d] : 0;
    __syncthreads();
    sc[t] += u1;
    sh[t] += u2;
    __syncthreads();
  }
  int blockbase = sc[blockIdx.x] - sv[blockIdx.x];
  int run = blockbase + sh[t] - s;
  int hv[4] = {h.x, h.y, h.z, h.w};
#pragma unroll
  for (int j = 0; j < 4; ++j) {
    int g = g4 * 4 + j;
    if (g < nc) { kstart[g] = run; kfill[g] = run; }
    else        { int q = g - nc; qstart[q] = run - Mtot; qfill[q] = run - Mtot; }
    run += hv[j];
  }
  if (blockIdx.x == 0 && t == 0) { kstart[nc] = Mtot; qstart[nc] = Ntot; }
}

// ---- scatter knowns (packed) and queries (packed, slot order) ----
__global__ __launch_bounds__(256) void scatter_k(
    const float* __restrict__ known, int Mtot, int Mi,
    const float* __restrict__ unknown, int Ntot,
    const int* __restrict__ kcell, const int* __restrict__ qcell,
    int* __restrict__ kfill, int* __restrict__ qfill,
    f32x4* __restrict__ k4s, int* __restrict__ korder,
    f32x4* __restrict__ u4s, int* __restrict__ qorder) {
  int i = blockIdx.x * 256 + threadIdx.x;
  if (i < Mtot) {
    int slot = atomicAdd(&kfill[kcell[i]], 1);
    float x = known[(size_t)i * 3], y = known[(size_t)i * 3 + 1], z = known[(size_t)i * 3 + 2];
    f32x4 v;
    v[0] = -2.f * x; v[1] = -2.f * y; v[2] = -2.f * z;
    v[3] = x * x + y * y + z * z;
    k4s[slot] = v;
    korder[slot] = i - (i / Mi) * Mi;   // batch-local index
  }
  if (i < Ntot) {
    int slot = atomicAdd(&qfill[qcell[i]], 1);
    float x = unknown[(size_t)i * 3], y = unknown[(size_t)i * 3 + 1], z = unknown[(size_t)i * 3 + 2];
    f32x4 v;
    v[0] = x; v[1] = y; v[2] = z;
    v[3] = __fmaf_rn(x, x, __fmaf_rn(y, y, z * z));
    u4s[slot] = v;
    qorder[slot] = i;
  }
}

// ---- scan rows of a (2R+1)^3 box (retry path) ----
static __device__ __forceinline__ void scan_box_strided(
    int R, int sub, int stride, int cx, int cy, int cz, int cellbase,
    const int* __restrict__ cstart, const f32x4* __restrict__ k4s,
    const int* __restrict__ korder,
    float ux, float uy, float uz,
    float& b0, float& b1, float& b2, int& j0, int& j1, int& j2) {
  int zlo = max(cz - R, 0), zhi = min(cz + R, GRID - 1);
  int ylo = max(cy - R, 0), yhi = min(cy + R, GRID - 1);
  int xlo = max(cx - R, 0), xhi = min(cx + R, GRID - 1);
  int ny = yhi - ylo + 1;
  int nrows = (zhi - zlo + 1) * ny;
  for (int rid = sub; rid < nrows; rid += stride) {
    int zz = rid / ny;
    int y  = ylo + (rid - zz * ny);
    int row = cellbase + ((zlo + zz) * GRID + y) * GRID;
    int s = cstart[row + xlo];
    int e = cstart[row + xhi + 1];
    for (int i = s; i < e; ++i) {
      f32x4 k = k4s[i];
      float d = __fmaf_rn(ux, k[0], __fmaf_rn(uy, k[1], __fmaf_rn(uz, k[2], k[3])));
      int m = korder[i];
      INSF(d, m);
    }
  }
}

// ---- weight-write helper ----
static __device__ __forceinline__ void write_result(
    float* __restrict__ w, int* __restrict__ idx, int p, float uu,
    float b0, float b1, float b2, int j0, int j1, int j2) {
  float d0 = sqrtf(fmaxf(b0 + uu, 0.f));
  float d1 = sqrtf(fmaxf(b1 + uu, 0.f));
  float d2 = sqrtf(fmaxf(b2 + uu, 0.f));
  float r0 = 1.f / (d0 + 1e-8f);
  float r1 = 1.f / (d1 + 1e-8f);
  float r2 = 1.f / (d2 + 1e-8f);
  float rs = 1.f / (r0 + r1 + r2);
  size_t o = (size_t)p * 3;
  w[o] = r0 * rs; w[o + 1] = r1 * rs; w[o + 2] = r2 * rs;
  idx[o] = j0; idx[o + 1] = j1; idx[o + 2] = j2;
}

// ---- pass 1: R=1 box, 16 sub-lanes/query, ILP2, exact coverage ----
__global__ __launch_bounds__(256) void knn_grid_k(
    const f32x4* __restrict__ u4s, const int* __restrict__ qorder,
    const int* __restrict__ cstart, const f32x4* __restrict__ k4s,
    const int* __restrict__ korder, int Ni,
    float* __restrict__ w, int* __restrict__ idx,
    int* __restrict__ rcnt, int* __restrict__ rlist, float* __restrict__ rd3) {
  int nwc = gridDim.x * 4;                    // wave-chunks (Ntot/QPW), pow2
  int gw  = blockIdx.x * 4 + (threadIdx.x >> 6);
  int wchunk = (gw * 997) & (nwc - 1);
  int s   = wchunk * QPW + ((threadIdx.x & 63) / SUBW);
  int sub = threadIdx.x & (SUBW - 1);
  f32x4 u4 = u4s[s];
  int p = qorder[s];
  int b = p / Ni;
  float ux = u4[0], uy = u4[1], uz = u4[2], uu = u4[3];
  int cx = cellco(ux), cy = cellco(uy), cz = cellco(uz);
  int cellbase = b * NCELL;
  int xlo = max(cx - 1, 0), xhi = min(cx + 1, GRID - 1);

  // exact coverage radius: h * (1 + min fractional distance to own-cell wall)
  float fx = (ux + OFF) * INVH - cx;
  float fy = (uy + OFF) * INVH - cy;
  float fz = (uz + OFF) * INVH - cz;
  float mf = fminf(fminf(fminf(fx, 1.f - fx), fminf(fy, 1.f - fy)),
                   fminf(fz, 1.f - fz));
  float cov = H * (1.f + fmaxf(mf, 0.f));
  float covsq = cov * cov;

  // prefetch all 9 row-ranges
  int cs[9], ce[9];
#pragma unroll
  for (int q = 0; q < 9; ++q) {
    int z = cz + (q / 3) - 1;
    int y = cy + (q % 3) - 1;
    bool valid = ((unsigned)z < GRID) && ((unsigned)y < GRID);
    int row = cellbase + (z * GRID + y) * GRID;
    int a0 = valid ? row + xlo : cellbase;
    int a1 = valid ? row + xhi + 1 : cellbase;
    cs[q] = cstart[a0];
    ce[q] = cstart[a1];
  }

  // dual top-3 accumulators (independent chains -> 2x ILP)
  float b0 = 3e38f, b1 = 3e38f, b2 = 3e38f;
  int   j0 = 0,     j1 = 0,     j2 = 0;
  float e0 = 3e38f, e1 = 3e38f, e2 = 3e38f;
  int   f0 = 0,     f1 = 0,     f2 = 0;
#pragma unroll
  for (int q = 0; q < 9; ++q) {
    int i = cs[q] + sub;
    int e = ce[q];
    for (; i + SUBW < e; i += 2 * SUBW) {
      f32x4 kA = k4s[i];
      f32x4 kB = k4s[i + SUBW];
      int mA = korder[i];
      int mB = korder[i + SUBW];
      float dA = __fmaf_rn(ux, kA[0], __fmaf_rn(uy, kA[1], __fmaf_rn(uz, kA[2], kA[3])));
      float dB = __fmaf_rn(ux, kB[0], __fmaf_rn(uy, kB[1], __fmaf_rn(uz, kB[2], kB[3])));
      INS3(b0, b1, b2, j0, j1, j2, dA, mA);
      INS3(e0, e1, e2, f0, f1, f2, dB, mB);
    }
    if (i < e) {
      f32x4 kA = k4s[i];
      int mA = korder[i];
      float dA = __fmaf_rn(ux, kA[0], __fmaf_rn(uy, kA[1], __fmaf_rn(uz, kA[2], kA[3])));
      INS3(b0, b1, b2, j0, j1, j2, dA, mA);
    }
  }
  INSF(e0, f0); INSF(e1, f1); INSF(e2, f2);   // merge B into A
  MERGE3(1, SUBW / 2);

  float d3sq = b2 + uu;
  bool ok = d3sq <= covsq;

  if (sub == 0) {
    if (ok) {
      write_result(w, idx, p, uu, b0, b1, b2, j0, j1, j2);
    } else {
      int t = atomicAdd(rcnt, 1);
      rlist[t] = s;
      rd3[t] = d3sq;
    }
  }
}

// ---- retry: one wave per deferred query, grid-stride balanced ----
__global__ __launch_bounds__(256) void knn_retry_k(
    const f32x4* __restrict__ u4s, const int* __restrict__ qorder,
    const int* __restrict__ rlist, const float* __restrict__ rd3,
    const int* __restrict__ rcnt,
    const int* __restrict__ cstart, const f32x4* __restrict__ k4s,
    const int* __restrict__ korder, int Ni,
    float* __restrict__ w, int* __restrict__ idx) {
  int lane = threadIdx.x & 63;
  int wv   = blockIdx.x * 4 + (threadIdx.x >> 6);
  int nw   = gridDim.x * 4;
  int cnt  = rcnt[0];
  for (int q = wv; q < cnt; q += nw) {
    int sq = rlist[q];
    f32x4 u4 = u4s[sq];
    int p = qorder[sq];
    int b = p / Ni;
    float ux = u4[0], uy = u4[1], uz = u4[2], uu = u4[3];
    int cx = cellco(ux), cy = cellco(uy), cz = cellco(uz);
    int cellbase = b * NCELL;

    float d3sq = rd3[q];
    int Rc = 1;
    float b0, b1, b2; int j0, j1, j2;
    bool ok = false;
    while (!ok) {
      if (d3sq < 1e30f) {
        Rc = max((int)ceilf(sqrtf(fmaxf(d3sq, 0.f)) * INVH), Rc + 1);
      } else {
        Rc = Rc * 2;
      }
      Rc = min(Rc, GRID);
      b0 = b1 = b2 = 3e38f; j0 = j1 = j2 = 0;
      scan_box_strided(Rc, lane, 64, cx, cy, cz, cellbase, cstart, k4s, korder,
                       ux, uy, uz, b0, b1, b2, j0, j1, j2);
      MERGE3(1, 32);
      d3sq = b2 + uu;
      float cov = (float)Rc * H;
      ok = (d3sq <= cov * cov) || (Rc >= GRID);
    }
    if (lane == 0)
      write_result(w, idx, p, uu, b0, b1, b2, j0, j1, j2);
  }
}

// ================= fused GEMM tier =================
template <bool F32OUT>
static __device__ __forceinline__ void gemm_half(
    const short* xs, const short* Ws, int row0,
    float* yf, __hip_bfloat16* yb, float* ls, float* lq) {
  int t = threadIdx.x;
  int lane = t & 63;
  int wv = t >> 6;
  int r = lane & 15, g = lane >> 4;
  int tile = wv >> 1, half = wv & 1;
  int trow = tile * 16;

  bf16x8 a[4];
#pragma unroll
  for (int q = 0; q < 4; ++q)
    a[q] = *reinterpret_cast<const bf16x8*>(&xs[(trow + r) * XPAD + g * 8 + q * 32]);

  int orow = row0 + trow + g * 4;
#pragma unroll
  for (int ct = 0; ct < 4; ++ct) {
    int ocol = half * 64 + ct * 16 + r;
    f32x4 acc = {0.f, 0.f, 0.f, 0.f};
    size_t bbase = (size_t)ocol * 128 + g * 8;
#pragma unroll
    for (int q = 0; q < 4; ++q) {
      bf16x8 bfr = *reinterpret_cast<const bf16x8*>(Ws + bbase + q * 32);
      acc = __builtin_amdgcn_mfma_f32_16x16x32_bf16(a[q], bfr, acc, 0, 0, 0);
    }
    if (F32OUT) {
#pragma unroll
      for (int i = 0; i < 4; ++i)
        yf[(size_t)(orow + i) * 128 + ocol] = acc[i];
    } else {
#pragma unroll
      for (int i = 0; i < 4; ++i)
        yb[(size_t)(orow + i) * 128 + ocol] = __float2bfloat16(acc[i]);
    }
    float s  = acc[0] + acc[1] + acc[2] + acc[3];
    float q2 = acc[0] * acc[0] + acc[1] * acc[1] + acc[2] * acc[2] + acc[3] * acc[3];
    s  += __shfl_xor(s, 16);  s  += __shfl_xor(s, 32);
    q2 += __shfl_xor(q2, 16); q2 += __shfl_xor(q2, 32);
    if (g == 0) {
      atomicAdd(&ls[ocol], s);
      atomicAdd(&lq[ocol], q2);
    }
  }
}

// ---- layer1: interp+concat staged to LDS, GEMM, bf16 out, stats ----
__global__ __launch_bounds__(256) void gemm1_fused_k(
    const float* __restrict__ kf, const float* __restrict__ uf,
    const float* __restrict__ wgt, const int* __restrict__ idx,
    const __hip_bfloat16* __restrict__ Wb, __hip_bfloat16* __restrict__ Yb,
    float* __restrict__ stats, int Ni, int Mi) {
  __shared__ short xs[32 * XPAD];
  __shared__ float ls[128], lq[128];
  int t = threadIdx.x;
  if (t < 128) { ls[t] = 0.f; lq[t] = 0.f; }
  int row0 = blockIdx.x * 32;

  int rr = t >> 3, c0 = (t & 7) * 16;
  int p = row0 + rr;
  short tmp[16];
  if (c0 < 64) {
    size_t o = (size_t)p * 3;
    float w0 = wgt[o], w1 = wgt[o + 1], w2 = wgt[o + 2];
    int i0 = idx[o], i1 = idx[o + 1], i2 = idx[o + 2];
    int b = p / Ni;
    const float* kfb = kf + (size_t)b * Mi * 64 + c0;
    const f32x4* r0p = reinterpret_cast<const f32x4*>(kfb + (size_t)i0 * 64);
    const f32x4* r1p = reinterpret_cast<const f32x4*>(kfb + (size_t)i1 * 64);
    const f32x4* r2p = reinterpret_cast<const f32x4*>(kfb + (size_t)i2 * 64);
#pragma unroll
    for (int j = 0; j < 4; ++j) {
      f32x4 av = r0p[j], bv = r1p[j], cv = r2p[j];
#pragma unroll
      for (int e = 0; e < 4; ++e)
        tmp[j * 4 + e] = f2bs(w0 * av[e] + w1 * bv[e] + w2 * cv[e]);
    }
  } else {
    const f32x4* ufp = reinterpret_cast<const f32x4*>(uf + (size_t)p * 64 + (c0 - 64));
#pragma unroll
    for (int j = 0; j < 4; ++j) {
      f32x4 av = ufp[j];
#pragma unroll
      for (int e = 0; e < 4; ++e)
        tmp[j * 4 + e] = f2bs(av[e]);
    }
  }
  *reinterpret_cast<bf16x8*>(&xs[rr * XPAD + c0])     = *reinterpret_cast<bf16x8*>(&tmp[0]);
  *reinterpret_cast<bf16x8*>(&xs[rr * XPAD + c0 + 8]) = *reinterpret_cast<bf16x8*>(&tmp[8]);
  __syncthreads();

  gemm_half<false>(xs, reinterpret_cast<const short*>(Wb), row0, nullptr, Yb, ls, lq);

  __syncthreads();
  if (t < 128) {
    int rep = blockIdx.x & (NREP - 1);
    atomicAdd(&stats[rep * 256 + t], ls[t]);
    atomicAdd(&stats[rep * 256 + 128 + t], lq[t]);
  }
}

// ---- layer2: AB1 from stats in prologue, BN1+ReLU staged, GEMM, bf16 out ----
__global__ __launch_bounds__(256) void gemm2_bn_k(
    const __hip_bfloat16* __restrict__ Y1, const float* __restrict__ stats,
    const float* __restrict__ g1, const float* __restrict__ b1v, float invN,
    const __hip_bfloat16* __restrict__ Wb, __hip_bfloat16* __restrict__ Yb2,
    float* __restrict__ stats2) {
  __shared__ short xs[32 * XPAD];
  __shared__ float ls[128], lq[128];
  __shared__ float ABs[256];
  int t = threadIdx.x;
  if (t < 128) {
    float s = 0.f, q = 0.f;
#pragma unroll
    for (int rpl = 0; rpl < NREP; ++rpl) {
      s += stats[rpl * 256 + t];
      q += stats[rpl * 256 + 128 + t];
    }
    float mu  = s * invN;
    float var = q * invN - mu * mu;
    float A = rsqrtf(var + 1e-5f) * g1[t];
    ABs[t] = A;
    ABs[128 + t] = b1v[t] - mu * A;
    ls[t] = 0.f; lq[t] = 0.f;
  }
  __syncthreads();
  int row0 = blockIdx.x * 32;

  int rr = t >> 3, c0 = (t & 7) * 16;
  int p = row0 + rr;
  const short* Ys = reinterpret_cast<const short*>(Y1);
  bf16x8 v0 = *reinterpret_cast<const bf16x8*>(Ys + (size_t)p * 128 + c0);
  bf16x8 v1 = *reinterpret_cast<const bf16x8*>(Ys + (size_t)p * 128 + c0 + 8);
  short tmp[16];
#pragma unroll
  for (int j = 0; j < 8; ++j)
    tmp[j] = f2bs(fmaxf(bs2f(v0[j]) * ABs[c0 + j] + ABs[128 + c0 + j], 0.f));
#pragma unroll
  for (int j = 0; j < 8; ++j)
    tmp[8 + j] = f2bs(fmaxf(bs2f(v1[j]) * ABs[c0 + 8 + j] + ABs[128 + c0 + 8 + j], 0.f));
  *reinterpret_cast<bf16x8*>(&xs[rr * XPAD + c0])     = *reinterpret_cast<bf16x8*>(&tmp[0]);
  *reinterpret_cast<bf16x8*>(&xs[rr * XPAD + c0 + 8]) = *reinterpret_cast<bf16x8*>(&tmp[8]);
  __syncthreads();

  gemm_half<false>(xs, reinterpret_cast<const short*>(Wb), row0, nullptr, Yb2, ls, lq);

  __syncthreads();
  if (t < 128) {
    int rep = blockIdx.x & (NREP - 1);
    atomicAdd(&stats2[rep * 256 + t], ls[t]);
    atomicAdd(&stats2[rep * 256 + 128 + t], lq[t]);
  }
}

// ---- BN2+ReLU: AB2 from stats2 in prologue, bf16 in -> f32 out ----
__global__ __launch_bounds__(256) void bnrelu_out_k(
    const __hip_bfloat16* __restrict__ Y, const float* __restrict__ stats2,
    const float* __restrict__ g2, const float* __restrict__ b2v, float invN,
    float* __restrict__ Out, long n8) {
  __shared__ float ABs[256];
  int t = threadIdx.x;
  if (t < 128) {
    float s = 0.f, q = 0.f;
#pragma unroll
    for (int rpl = 0; rpl < NREP; ++rpl) {
      s += stats2[rpl * 256 + t];
      q += stats2[rpl * 256 + 128 + t];
    }
    float mu  = s * invN;
    float var = q * invN - mu * mu;
    float A = rsqrtf(var + 1e-5f) * g2[t];
    ABs[t] = A;
    ABs[128 + t] = b2v[t] - mu * A;
  }
  __syncthreads();
  long i = (long)blockIdx.x * 256 + t;
  long stride = (long)gridDim.x * 256;
  const bf16x8* Y8 = reinterpret_cast<const bf16x8*>(Y);
  for (; i < n8; i += stride) {
    bf16x8 y = Y8[i];
    int c0 = (int)((i * 8) & 127);
    f32x4 o0, o1;
#pragma unroll
    for (int j = 0; j < 4; ++j)
      o0[j] = fmaxf(bs2f(y[j]) * ABs[c0 + j] + ABs[128 + c0 + j], 0.f);
#pragma unroll
    for (int j = 0; j < 4; ++j)
      o1[j] = fmaxf(bs2f(y[4 + j]) * ABs[c0 + 4 + j] + ABs[128 + c0 + 4 + j], 0.f);
    reinterpret_cast<f32x4*>(Out)[i * 2]     = o0;
    reinterpret_cast<f32x4*>(Out)[i * 2 + 1] = o1;
  }
}

extern "C" void kernel_launch(void* const* d_in, const int* in_sizes, int n_in,
                              void* d_out, int out_size, void* d_ws, size_t ws_size,
                              hipStream_t stream) {
  const float* unknown = (const float*)d_in[0];
  const float* known   = (const float*)d_in[2];
  const float* uf      = (const float*)d_in[4];
  const float* kf      = (const float*)d_in[5];
  const float* W1      = (const float*)d_in[6];
  const float* g1      = (const float*)d_in[7];
  const float* b1      = (const float*)d_in[8];
  const float* W2      = (const float*)d_in[9];
  const float* g2      = (const float*)d_in[10];
  const float* b2      = (const float*)d_in[11];

  int B    = in_sizes[1];
  int Ntot = in_sizes[0] / 3;
  int Mtot = in_sizes[2] / 3;
  int Ni = Ntot / B, Mi = Mtot / B;
  int nc = B * NCELL;
  int n2 = 2 * nc;

  char* ws = (char*)d_ws;
  size_t off = 0;
  auto alloc = [&](size_t bytes) {
    void* p = ws + off;
    off += (bytes + 255) & ~(size_t)255;
    return p;
  };
  // zeroed region: [stats(2 layers x NREP x 256) | rcnt | khist+qhist]
  float* stats  = (float*)alloc(2 * NREP * 256 * 4);
  int*   rcnt   = (int*)alloc(4);
  int*   khist  = (int*)alloc((size_t)n2 * 4);
  int*   qhist  = khist + nc;
  size_t zero_bytes = (size_t)((char*)(khist + n2) - (char*)stats);
  int*   kstart = (int*)alloc((size_t)(nc + 1) * 4);
  int*   qstart = (int*)alloc((size_t)(nc + 1) * 4);
  int*   kfill  = (int*)alloc((size_t)nc * 4);
  int*   qfill  = (int*)alloc((size_t)nc * 4);
  int*   kcell  = (int*)alloc((size_t)Mtot * 4);
  int*   qcell  = (int*)alloc((size_t)Ntot * 4);
  int*   korder = (int*)alloc((size_t)Mtot * 4);
  int*   qorder = (int*)alloc((size_t)Ntot * 4);
  int*   bsum   = (int*)alloc((size_t)(n2 / 1024) * 4);
  int*   rlist  = (int*)alloc((size_t)Ntot * 4);
  float* rd3    = (float*)alloc((size_t)Ntot * 4);
  f32x4* k4s    = (f32x4*)alloc((size_t)Mtot * 16);
  f32x4* u4s    = (f32x4*)alloc((size_t)Ntot * 16);
  float* wgt    = (float*)alloc((size_t)Ntot * 3 * 4);
  int*   idx    = (int*)alloc((size_t)Ntot * 3 * 4);
  __hip_bfloat16* y1b = (__hip_bfloat16*)alloc((size_t)Ntot * 128 * 2);
  __hip_bfloat16* y2b = (__hip_bfloat16*)alloc((size_t)Ntot * 128 * 2);
  __hip_bfloat16* Wb1 = (__hip_bfloat16*)alloc(128 * 128 * 2);
  __hip_bfloat16* Wb2 = (__hip_bfloat16*)alloc(128 * 128 * 2);

  float* y2 = (float*)d_out;
  long n8 = (long)Ntot * 128 / 8;
  float invN = 1.0f / (float)Ntot;
  int nb = n2 / 1024;
  float* stats2 = stats + NREP * 256;
  int zn4 = (int)(zero_bytes / 16);

  zero_k<<<(zn4 + 255) / 256, 256, 0, stream>>>((int4*)stats, zn4);
  hist_k<<<(Ntot + 255) / 256, 256, 0, stream>>>(known, Mtot, Mi, unknown, Ntot,
                                                 khist, qhist, kcell, qcell, W1, W2, Wb1, Wb2);
  scan1_k<<<nb, 256, 0, stream>>>((const int4*)khist, bsum);
  scan3_k<<<nb, 256, 0, stream>>>((const int4*)khist, bsum, nb, kstart, kfill,
                                  qstart, qfill, nc, Mtot, Ntot);
  scatter_k<<<(Ntot + 255) / 256, 256, 0, stream>>>(known, Mtot, Mi, unknown, Ntot,
                                                    kcell, qcell, kfill, qfill, k4s, korder, u4s, qorder);
  knn_grid_k<<<Ntot / (QPW * 4), 256, 0, stream>>>(u4s, qorder, kstart, k4s, korder, Ni,
                                                   wgt, idx, rcnt, rlist, rd3);
  knn_retry_k<<<512, 256, 0, stream>>>(u4s, qorder, rlist, rd3, rcnt,
                                       kstart, k4s, korder, Ni, wgt, idx);
  gemm1_fused_k<<<Ntot / 32, 256, 0, stream>>>(kf, uf, wgt, idx, Wb1, y1b, stats, Ni, Mi);
  gemm2_bn_k<<<Ntot / 32, 256, 0, stream>>>(y1b, stats, g1, b1, invN, Wb2, y2b, stats2);
  bnrelu_out_k<<<2048, 256, 0, stream>>>(y2b, stats2, g2, b2, invN, y2, n8);
}

// Round 21
// 143.735 us; speedup vs baseline: 1.1376x; 1.1376x over previous
//
#include <hip/hip_runtime.h>
#include <hip/hip_bf16.h>

#define GRID  32
#define NCELL (GRID * GRID * GRID)
#define H     0.3125f
#define INVH  3.2f
#define OFF   5.0f
#define SUBW  8
#define XPAD  136
#define NREP  16

using f32x4  = __attribute__((ext_vector_type(4))) float;
using bf16x8 = __attribute__((ext_vector_type(8))) short;

static __device__ inline short f2bs(float f) {
  __hip_bfloat16 h = __float2bfloat16(f);
  return __builtin_bit_cast(short, h);
}
static __device__ inline float bs2f(short s) {
  return __bfloat162float(__builtin_bit_cast(__hip_bfloat16, s));
}
static __device__ inline int cellco(float x) {
  int c = (int)((x + OFF) * INVH);
  return min(GRID - 1, max(0, c));
}

// branchless sorted-insert into named top-3 set
#define INS3(B0, B1, B2, J0, J1, J2, dv, mv)           \
  {                                                    \
    bool q0 = dv < B0, q1 = dv < B1, q2 = dv < B2;     \
    float P0 = B0, P1 = B1; int Q0 = J0, Q1 = J1;      \
    B2 = q1 ? P1 : (q2 ? dv : B2);                     \
    J2 = q1 ? Q1 : (q2 ? mv : J2);                     \
    B1 = q0 ? P0 : (q1 ? dv : P1);                     \
    J1 = q0 ? Q0 : (q1 ? mv : Q1);                     \
    B0 = q0 ? dv : P0;                                 \
    J0 = q0 ? mv : Q0;                                 \
  }
#define INSF(dv, mv) INS3(b0, b1, b2, j0, j1, j2, dv, mv)

#define MERGE3(lo_mk, hi_mk)                                                        \
  for (int mk = lo_mk; mk <= hi_mk; mk <<= 1) {                                     \
    float ob0 = __shfl_xor(b0, mk), ob1 = __shfl_xor(b1, mk), ob2 = __shfl_xor(b2, mk); \
    int   oj0 = __shfl_xor(j0, mk), oj1 = __shfl_xor(j1, mk), oj2 = __shfl_xor(j2, mk); \
    INSF(ob0, oj0); INSF(ob1, oj1); INSF(ob2, oj2);                                 \
  }

// ---- fast workspace zeroing ----
__global__ __launch_bounds__(256) void zero_k(int4* __restrict__ dst, int n4) {
  int i = blockIdx.x * 256 + threadIdx.x;
  if (i < n4) dst[i] = int4{0, 0, 0, 0};
}

// ---- histogram knowns + queries into cells; convert W to bf16 ----
__global__ __launch_bounds__(256) void hist_k(
    const float* __restrict__ known, int Mtot, int Mi,
    const float* __restrict__ unknown, int Ntot,
    int* __restrict__ khist, int* __restrict__ qhist,
    int* __restrict__ kcell, int* __restrict__ qcell,
    const float* __restrict__ W1, const float* __restrict__ W2,
    __hip_bfloat16* __restrict__ Wb1, __hip_bfloat16* __restrict__ Wb2) {
  int i = blockIdx.x * 256 + threadIdx.x;
  if (i < 128 * 128) {
    Wb1[i] = __float2bfloat16(W1[i]);
    Wb2[i] = __float2bfloat16(W2[i]);
  }
  if (i < Mtot) {
    int b = i / Mi;
    float x = known[(size_t)i * 3], y = known[(size_t)i * 3 + 1], z = known[(size_t)i * 3 + 2];
    int c = b * NCELL + (cellco(z) * GRID + cellco(y)) * GRID + cellco(x);
    kcell[i] = c;
    atomicAdd(&khist[c], 1);
  }
  if (i < Ntot) {
    int Ni = Ntot / (Mtot / Mi);
    int b = i / Ni;
    float x = unknown[(size_t)i * 3], y = unknown[(size_t)i * 3 + 1], z = unknown[(size_t)i * 3 + 2];
    int c = b * NCELL + (cellco(z) * GRID + cellco(y)) * GRID + cellco(x);
    qcell[i] = c;
    atomicAdd(&qhist[c], 1);
  }
}

// ---- scan1: per-block sums of combined [khist|qhist] ----
__global__ __launch_bounds__(256) void scan1_k(
    const int4* __restrict__ Hc4, int* __restrict__ bsum) {
  __shared__ int sh[256];
  int t = threadIdx.x;
  int4 h = Hc4[blockIdx.x * 256 + t];
  int s = h.x + h.y + h.z + h.w;
  sh[t] = s;
  __syncthreads();
  for (int d = 128; d > 0; d >>= 1) {
    if (t < d) sh[t] += sh[t + d];
    __syncthreads();
  }
  if (t == 0) bsum[blockIdx.x] = sh[0];
}

// ---- scan3: redundant bsum scan + local rescan + write start/fill ----
__global__ __launch_bounds__(256) void scan3_k(
    const int4* __restrict__ Hc4, const int* __restrict__ bsum, int nbk,
    int* __restrict__ kstart, int* __restrict__ kfill,
    int* __restrict__ qstart, int* __restrict__ qfill,
    int nc, int Mtot, int Ntot) {
  __shared__ int sh[256];
  __shared__ int sv[256], sc[256];
  int t = threadIdx.x;
  int v = (t < nbk) ? bsum[t] : 0;
  sv[t] = v; sc[t] = v;
  int g4 = blockIdx.x * 256 + t;
  int4 h = Hc4[g4];
  int s = h.x + h.y + h.z + h.w;
  sh[t] = s;
  __syncthreads();
  for (int d = 1; d < 256; d <<= 1) {
    int u1 = (t >= d) ? sc[t - d] : 0;
    int u2 = (t >= d) ? sh[t - d] : 0;
    __syncthreads();
    sc[t] += u1;
    sh[t] += u2;
    __syncthreads();
  }
  int blockbase = sc[blockIdx.x] - sv[blockIdx.x];
  int run = blockbase + sh[t] - s;
  int hv[4] = {h.x, h.y, h.z, h.w};
#pragma unroll
  for (int j = 0; j < 4; ++j) {
    int g = g4 * 4 + j;
    if (g < nc) { kstart[g] = run; kfill[g] = run; }
    else        { int q = g - nc; qstart[q] = run - Mtot; qfill[q] = run - Mtot; }
    run += hv[j];
  }
  if (blockIdx.x == 0 && t == 0) { kstart[nc] = Mtot; qstart[nc] = Ntot; }
}

// ---- scatter knowns (packed) and queries (packed, slot order) ----
__global__ __launch_bounds__(256) void scatter_k(
    const float* __restrict__ known, int Mtot, int Mi,
    const float* __restrict__ unknown, int Ntot,
    const int* __restrict__ kcell, const int* __restrict__ qcell,
    int* __restrict__ kfill, int* __restrict__ qfill,
    f32x4* __restrict__ k4s, int* __restrict__ korder,
    f32x4* __restrict__ u4s, int* __restrict__ qorder) {
  int i = blockIdx.x * 256 + threadIdx.x;
  if (i < Mtot) {
    int slot = atomicAdd(&kfill[kcell[i]], 1);
    float x = known[(size_t)i * 3], y = known[(size_t)i * 3 + 1], z = known[(size_t)i * 3 + 2];
    f32x4 v;
    v[0] = -2.f * x; v[1] = -2.f * y; v[2] = -2.f * z;
    v[3] = x * x + y * y + z * z;
    k4s[slot] = v;
    korder[slot] = i - (i / Mi) * Mi;   // batch-local index
  }
  if (i < Ntot) {
    int slot = atomicAdd(&qfill[qcell[i]], 1);
    float x = unknown[(size_t)i * 3], y = unknown[(size_t)i * 3 + 1], z = unknown[(size_t)i * 3 + 2];
    f32x4 v;
    v[0] = x; v[1] = y; v[2] = z;
    v[3] = __fmaf_rn(x, x, __fmaf_rn(y, y, z * z));
    u4s[slot] = v;
    qorder[slot] = i;
  }
}

// ---- scan rows of a (2R+1)^3 box (retry path) ----
static __device__ __forceinline__ void scan_box_strided(
    int R, int sub, int stride, int cx, int cy, int cz, int cellbase,
    const int* __restrict__ cstart, const f32x4* __restrict__ k4s,
    const int* __restrict__ korder,
    float ux, float uy, float uz,
    float& b0, float& b1, float& b2, int& j0, int& j1, int& j2) {
  int zlo = max(cz - R, 0), zhi = min(cz + R, GRID - 1);
  int ylo = max(cy - R, 0), yhi = min(cy + R, GRID - 1);
  int xlo = max(cx - R, 0), xhi = min(cx + R, GRID - 1);
  int ny = yhi - ylo + 1;
  int nrows = (zhi - zlo + 1) * ny;
  for (int rid = sub; rid < nrows; rid += stride) {
    int zz = rid / ny;
    int y  = ylo + (rid - zz * ny);
    int row = cellbase + ((zlo + zz) * GRID + y) * GRID;
    int s = cstart[row + xlo];
    int e = cstart[row + xhi + 1];
    for (int i = s; i < e; ++i) {
      f32x4 k = k4s[i];
      float d = __fmaf_rn(ux, k[0], __fmaf_rn(uy, k[1], __fmaf_rn(uz, k[2], k[3])));
      int m = korder[i];
      INSF(d, m);
    }
  }
}

// ---- weight-write helper ----
static __device__ __forceinline__ void write_result(
    float* __restrict__ w, int* __restrict__ idx, int p, float uu,
    float b0, float b1, float b2, int j0, int j1, int j2) {
  float d0 = sqrtf(fmaxf(b0 + uu, 0.f));
  float d1 = sqrtf(fmaxf(b1 + uu, 0.f));
  float d2 = sqrtf(fmaxf(b2 + uu, 0.f));
  float r0 = 1.f / (d0 + 1e-8f);
  float r1 = 1.f / (d1 + 1e-8f);
  float r2 = 1.f / (d2 + 1e-8f);
  float rs = 1.f / (r0 + r1 + r2);
  size_t o = (size_t)p * 3;
  w[o] = r0 * rs; w[o + 1] = r1 * rs; w[o + 2] = r2 * rs;
  idx[o] = j0; idx[o + 1] = j1; idx[o + 2] = j2;
}

// ---- pass 1: R=1 box, prefetched ranges, dual-accumulator ILP2, exact cov ----
__global__ __launch_bounds__(256) void knn_grid_k(
    const f32x4* __restrict__ u4s, const int* __restrict__ qorder,
    const int* __restrict__ cstart, const f32x4* __restrict__ k4s,
    const int* __restrict__ korder, int Ni,
    float* __restrict__ w, int* __restrict__ idx,
    int* __restrict__ rcnt, int* __restrict__ rlist, float* __restrict__ rd3) {
  int nwc = gridDim.x * 4;
  int gw  = blockIdx.x * 4 + (threadIdx.x >> 6);
  int wchunk = (gw * 997) & (nwc - 1);
  int s   = wchunk * 8 + ((threadIdx.x & 63) / SUBW);
  int sub = threadIdx.x & (SUBW - 1);
  f32x4 u4 = u4s[s];
  int p = qorder[s];
  int b = p / Ni;
  float ux = u4[0], uy = u4[1], uz = u4[2], uu = u4[3];
  int cx = cellco(ux), cy = cellco(uy), cz = cellco(uz);
  int cellbase = b * NCELL;
  int xlo = max(cx - 1, 0), xhi = min(cx + 1, GRID - 1);

  // exact coverage radius: h * (1 + min fractional distance to own-cell wall)
  float fx = (ux + OFF) * INVH - cx;
  float fy = (uy + OFF) * INVH - cy;
  float fz = (uz + OFF) * INVH - cz;
  float mf = fminf(fminf(fminf(fx, 1.f - fx), fminf(fy, 1.f - fy)),
                   fminf(fz, 1.f - fz));
  float cov = H * (1.f + fmaxf(mf, 0.f));
  float covsq = cov * cov;

  // prefetch all 9 row-ranges
  int cs[9], ce[9];
#pragma unroll
  for (int q = 0; q < 9; ++q) {
    int z = cz + (q / 3) - 1;
    int y = cy + (q % 3) - 1;
    bool valid = ((unsigned)z < GRID) && ((unsigned)y < GRID);
    int row = cellbase + (z * GRID + y) * GRID;
    int a0 = valid ? row + xlo : cellbase;
    int a1 = valid ? row + xhi + 1 : cellbase;
    cs[q] = cstart[a0];
    ce[q] = cstart[a1];
  }

  // dual top-3 accumulators (independent chains -> 2x ILP)
  float b0 = 3e38f, b1 = 3e38f, b2 = 3e38f;
  int   j0 = 0,     j1 = 0,     j2 = 0;
  float e0 = 3e38f, e1 = 3e38f, e2 = 3e38f;
  int   f0 = 0,     f1 = 0,     f2 = 0;
#pragma unroll
  for (int q = 0; q < 9; ++q) {
    int i = cs[q] + sub;
    int e = ce[q];
    for (; i + SUBW < e; i += 2 * SUBW) {
      f32x4 kA = k4s[i];
      f32x4 kB = k4s[i + SUBW];
      int mA = korder[i];
      int mB = korder[i + SUBW];
      float dA = __fmaf_rn(ux, kA[0], __fmaf_rn(uy, kA[1], __fmaf_rn(uz, kA[2], kA[3])));
      float dB = __fmaf_rn(ux, kB[0], __fmaf_rn(uy, kB[1], __fmaf_rn(uz, kB[2], kB[3])));
      INS3(b0, b1, b2, j0, j1, j2, dA, mA);
      INS3(e0, e1, e2, f0, f1, f2, dB, mB);
    }
    if (i < e) {
      f32x4 kA = k4s[i];
      int mA = korder[i];
      float dA = __fmaf_rn(ux, kA[0], __fmaf_rn(uy, kA[1], __fmaf_rn(uz, kA[2], kA[3])));
      INS3(b0, b1, b2, j0, j1, j2, dA, mA);
    }
  }
  INSF(e0, f0); INSF(e1, f1); INSF(e2, f2);   // merge B into A
  MERGE3(1, SUBW / 2);

  float d3sq = b2 + uu;
  bool ok = d3sq <= covsq;

  if (sub == 0) {
    if (ok) {
      write_result(w, idx, p, uu, b0, b1, b2, j0, j1, j2);
    } else {
      int t = atomicAdd(rcnt, 1);
      rlist[t] = s;
      rd3[t] = d3sq;
    }
  }
}

// ---- retry: one wave per deferred query, grid-stride balanced ----
__global__ __launch_bounds__(256) void knn_retry_k(
    const f32x4* __restrict__ u4s, const int* __restrict__ qorder,
    const int* __restrict__ rlist, const float* __restrict__ rd3,
    const int* __restrict__ rcnt,
    const int* __restrict__ cstart, const f32x4* __restrict__ k4s,
    const int* __restrict__ korder, int Ni,
    float* __restrict__ w, int* __restrict__ idx) {
  int lane = threadIdx.x & 63;
  int wv   = blockIdx.x * 4 + (threadIdx.x >> 6);
  int nw   = gridDim.x * 4;
  int cnt  = rcnt[0];
  for (int q = wv; q < cnt; q += nw) {
    int sq = rlist[q];
    f32x4 u4 = u4s[sq];
    int p = qorder[sq];
    int b = p / Ni;
    float ux = u4[0], uy = u4[1], uz = u4[2], uu = u4[3];
    int cx = cellco(ux), cy = cellco(uy), cz = cellco(uz);
    int cellbase = b * NCELL;

    float d3sq = rd3[q];
    int Rc = 1;
    float b0, b1, b2; int j0, j1, j2;
    bool ok = false;
    while (!ok) {
      if (d3sq < 1e30f) {
        Rc = max((int)ceilf(sqrtf(fmaxf(d3sq, 0.f)) * INVH), Rc + 1);
      } else {
        Rc = Rc * 2;
      }
      Rc = min(Rc, GRID);
      b0 = b1 = b2 = 3e38f; j0 = j1 = j2 = 0;
      scan_box_strided(Rc, lane, 64, cx, cy, cz, cellbase, cstart, k4s, korder,
                       ux, uy, uz, b0, b1, b2, j0, j1, j2);
      MERGE3(1, 32);
      d3sq = b2 + uu;
      float cov = (float)Rc * H;
      ok = (d3sq <= cov * cov) || (Rc >= GRID);
    }
    if (lane == 0)
      write_result(w, idx, p, uu, b0, b1, b2, j0, j1, j2);
  }
}

// ================= fused GEMM tier =================
template <bool F32OUT>
static __device__ __forceinline__ void gemm_half(
    const short* xs, const short* Ws, int row0,
    float* yf, __hip_bfloat16* yb, float* ls, float* lq) {
  int t = threadIdx.x;
  int lane = t & 63;
  int wv = t >> 6;
  int r = lane & 15, g = lane >> 4;
  int tile = wv >> 1, half = wv & 1;
  int trow = tile * 16;

  bf16x8 a[4];
#pragma unroll
  for (int q = 0; q < 4; ++q)
    a[q] = *reinterpret_cast<const bf16x8*>(&xs[(trow + r) * XPAD + g * 8 + q * 32]);

  int orow = row0 + trow + g * 4;
#pragma unroll
  for (int ct = 0; ct < 4; ++ct) {
    int ocol = half * 64 + ct * 16 + r;
    f32x4 acc = {0.f, 0.f, 0.f, 0.f};
    size_t bbase = (size_t)ocol * 128 + g * 8;
#pragma unroll
    for (int q = 0; q < 4; ++q) {
      bf16x8 bfr = *reinterpret_cast<const bf16x8*>(Ws + bbase + q * 32);
      acc = __builtin_amdgcn_mfma_f32_16x16x32_bf16(a[q], bfr, acc, 0, 0, 0);
    }
    if (F32OUT) {
#pragma unroll
      for (int i = 0; i < 4; ++i)
        yf[(size_t)(orow + i) * 128 + ocol] = acc[i];
    } else {
#pragma unroll
      for (int i = 0; i < 4; ++i)
        yb[(size_t)(orow + i) * 128 + ocol] = __float2bfloat16(acc[i]);
    }
    float s  = acc[0] + acc[1] + acc[2] + acc[3];
    float q2 = acc[0] * acc[0] + acc[1] * acc[1] + acc[2] * acc[2] + acc[3] * acc[3];
    s  += __shfl_xor(s, 16);  s  += __shfl_xor(s, 32);
    q2 += __shfl_xor(q2, 16); q2 += __shfl_xor(q2, 32);
    if (g == 0) {
      atomicAdd(&ls[ocol], s);
      atomicAdd(&lq[ocol], q2);
    }
  }
}

// ---- layer1: interp+concat staged to LDS, GEMM, bf16 out, stats ----
__global__ __launch_bounds__(256) void gemm1_fused_k(
    const float* __restrict__ kf, const float* __restrict__ uf,
    const float* __restrict__ wgt, const int* __restrict__ idx,
    const __hip_bfloat16* __restrict__ Wb, __hip_bfloat16* __restrict__ Yb,
    float* __restrict__ stats, int Ni, int Mi) {
  __shared__ short xs[32 * XPAD];
  __shared__ float ls[128], lq[128];
  int t = threadIdx.x;
  if (t < 128) { ls[t] = 0.f; lq[t] = 0.f; }
  int row0 = blockIdx.x * 32;

  int rr = t >> 3, c0 = (t & 7) * 16;
  int p = row0 + rr;
  short tmp[16];
  if (c0 < 64) {
    size_t o = (size_t)p * 3;
    float w0 = wgt[o], w1 = wgt[o + 1], w2 = wgt[o + 2];
    int i0 = idx[o], i1 = idx[o + 1], i2 = idx[o + 2];
    int b = p / Ni;
    const float* kfb = kf + (size_t)b * Mi * 64 + c0;
    const f32x4* r0p = reinterpret_cast<const f32x4*>(kfb + (size_t)i0 * 64);
    const f32x4* r1p = reinterpret_cast<const f32x4*>(kfb + (size_t)i1 * 64);
    const f32x4* r2p = reinterpret_cast<const f32x4*>(kfb + (size_t)i2 * 64);
#pragma unroll
    for (int j = 0; j < 4; ++j) {
      f32x4 av = r0p[j], bv = r1p[j], cv = r2p[j];
#pragma unroll
      for (int e = 0; e < 4; ++e)
        tmp[j * 4 + e] = f2bs(w0 * av[e] + w1 * bv[e] + w2 * cv[e]);
    }
  } else {
    const f32x4* ufp = reinterpret_cast<const f32x4*>(uf + (size_t)p * 64 + (c0 - 64));
#pragma unroll
    for (int j = 0; j < 4; ++j) {
      f32x4 av = ufp[j];
#pragma unroll
      for (int e = 0; e < 4; ++e)
        tmp[j * 4 + e] = f2bs(av[e]);
    }
  }
  *reinterpret_cast<bf16x8*>(&xs[rr * XPAD + c0])     = *reinterpret_cast<bf16x8*>(&tmp[0]);
  *reinterpret_cast<bf16x8*>(&xs[rr * XPAD + c0 + 8]) = *reinterpret_cast<bf16x8*>(&tmp[8]);
  __syncthreads();

  gemm_half<false>(xs, reinterpret_cast<const short*>(Wb), row0, nullptr, Yb, ls, lq);

  __syncthreads();
  if (t < 128) {
    int rep = blockIdx.x & (NREP - 1);
    atomicAdd(&stats[rep * 256 + t], ls[t]);
    atomicAdd(&stats[rep * 256 + 128 + t], lq[t]);
  }
}

// ---- layer2: AB1 from stats in prologue, BN1+ReLU staged, GEMM, bf16 out ----
__global__ __launch_bounds__(256) void gemm2_bn_k(
    const __hip_bfloat16* __restrict__ Y1, const float* __restrict__ stats,
    const float* __restrict__ g1, const float* __restrict__ b1v, float invN,
    const __hip_bfloat16* __restrict__ Wb, __hip_bfloat16* __restrict__ Yb2,
    float* __restrict__ stats2) {
  __shared__ short xs[32 * XPAD];
  __shared__ float ls[128], lq[128];
  __shared__ float ABs[256];
  int t = threadIdx.x;
  if (t < 128) {
    float s = 0.f, q = 0.f;
#pragma unroll
    for (int rpl = 0; rpl < NREP; ++rpl) {
      s += stats[rpl * 256 + t];
      q += stats[rpl * 256 + 128 + t];
    }
    float mu  = s * invN;
    float var = q * invN - mu * mu;
    float A = rsqrtf(var + 1e-5f) * g1[t];
    ABs[t] = A;
    ABs[128 + t] = b1v[t] - mu * A;
    ls[t] = 0.f; lq[t] = 0.f;
  }
  __syncthreads();
  int row0 = blockIdx.x * 32;

  int rr = t >> 3, c0 = (t & 7) * 16;
  int p = row0 + rr;
  const short* Ys = reinterpret_cast<const short*>(Y1);
  bf16x8 v0 = *reinterpret_cast<const bf16x8*>(Ys + (size_t)p * 128 + c0);
  bf16x8 v1 = *reinterpret_cast<const bf16x8*>(Ys + (size_t)p * 128 + c0 + 8);
  short tmp[16];
#pragma unroll
  for (int j = 0; j < 8; ++j)
    tmp[j] = f2bs(fmaxf(bs2f(v0[j]) * ABs[c0 + j] + ABs[128 + c0 + j], 0.f));
#pragma unroll
  for (int j = 0; j < 8; ++j)
    tmp[8 + j] = f2bs(fmaxf(bs2f(v1[j]) * ABs[c0 + 8 + j] + ABs[128 + c0 + 8 + j], 0.f));
  *reinterpret_cast<bf16x8*>(&xs[rr * XPAD + c0])     = *reinterpret_cast<bf16x8*>(&tmp[0]);
  *reinterpret_cast<bf16x8*>(&xs[rr * XPAD + c0 + 8]) = *reinterpret_cast<bf16x8*>(&tmp[8]);
  __syncthreads();

  gemm_half<false>(xs, reinterpret_cast<const short*>(Wb), row0, nullptr, Yb2, ls, lq);

  __syncthreads();
  if (t < 128) {
    int rep = blockIdx.x & (NREP - 1);
    atomicAdd(&stats2[rep * 256 + t], ls[t]);
    atomicAdd(&stats2[rep * 256 + 128 + t], lq[t]);
  }
}

// ---- BN2+ReLU: AB2 from stats2 in prologue, bf16 in -> f32 out ----
__global__ __launch_bounds__(256) void bnrelu_out_k(
    const __hip_bfloat16* __restrict__ Y, const float* __restrict__ stats2,
    const float* __restrict__ g2, const float* __restrict__ b2v, float invN,
    float* __restrict__ Out, long n8) {
  __shared__ float ABs[256];
  int t = threadIdx.x;
  if (t < 128) {
    float s = 0.f, q = 0.f;
#pragma unroll
    for (int rpl = 0; rpl < NREP; ++rpl) {
      s += stats2[rpl * 256 + t];
      q += stats2[rpl * 256 + 128 + t];
    }
    float mu  = s * invN;
    float var = q * invN - mu * mu;
    float A = rsqrtf(var + 1e-5f) * g2[t];
    ABs[t] = A;
    ABs[128 + t] = b2v[t] - mu * A;
  }
  __syncthreads();
  long i = (long)blockIdx.x * 256 + t;
  long stride = (long)gridDim.x * 256;
  const bf16x8* Y8 = reinterpret_cast<const bf16x8*>(Y);
  for (; i < n8; i += stride) {
    bf16x8 y = Y8[i];
    int c0 = (int)((i * 8) & 127);
    f32x4 o0, o1;
#pragma unroll
    for (int j = 0; j < 4; ++j)
      o0[j] = fmaxf(bs2f(y[j]) * ABs[c0 + j] + ABs[128 + c0 + j], 0.f);
#pragma unroll
    for (int j = 0; j < 4; ++j)
      o1[j] = fmaxf(bs2f(y[4 + j]) * ABs[c0 + 4 + j] + ABs[128 + c0 + 4 + j], 0.f);
    reinterpret_cast<f32x4*>(Out)[i * 2]     = o0;
    reinterpret_cast<f32x4*>(Out)[i * 2 + 1] = o1;
  }
}

extern "C" void kernel_launch(void* const* d_in, const int* in_sizes, int n_in,
                              void* d_out, int out_size, void* d_ws, size_t ws_size,
                              hipStream_t stream) {
  const float* unknown = (const float*)d_in[0];
  const float* known   = (const float*)d_in[2];
  const float* uf      = (const float*)d_in[4];
  const float* kf      = (const float*)d_in[5];
  const float* W1      = (const float*)d_in[6];
  const float* g1      = (const float*)d_in[7];
  const float* b1      = (const float*)d_in[8];
  const float* W2      = (const float*)d_in[9];
  const float* g2      = (const float*)d_in[10];
  const float* b2      = (const float*)d_in[11];

  int B    = in_sizes[1];
  int Ntot = in_sizes[0] / 3;
  int Mtot = in_sizes[2] / 3;
  int Ni = Ntot / B, Mi = Mtot / B;
  int nc = B * NCELL;
  int n2 = 2 * nc;

  char* ws = (char*)d_ws;
  size_t off = 0;
  auto alloc = [&](size_t bytes) {
    void* p = ws + off;
    off += (bytes + 255) & ~(size_t)255;
    return p;
  };
  // zeroed region: [stats(2 layers x NREP x 256) | rcnt | khist+qhist]
  float* stats  = (float*)alloc(2 * NREP * 256 * 4);
  int*   rcnt   = (int*)alloc(4);
  int*   khist  = (int*)alloc((size_t)n2 * 4);
  int*   qhist  = khist + nc;
  size_t zero_bytes = (size_t)((char*)(khist + n2) - (char*)stats);
  int*   kstart = (int*)alloc((size_t)(nc + 1) * 4);
  int*   qstart = (int*)alloc((size_t)(nc + 1) * 4);
  int*   kfill  = (int*)alloc((size_t)nc * 4);
  int*   qfill  = (int*)alloc((size_t)nc * 4);
  int*   kcell  = (int*)alloc((size_t)Mtot * 4);
  int*   qcell  = (int*)alloc((size_t)Ntot * 4);
  int*   korder = (int*)alloc((size_t)Mtot * 4);
  int*   qorder = (int*)alloc((size_t)Ntot * 4);
  int*   bsum   = (int*)alloc((size_t)(n2 / 1024) * 4);
  int*   rlist  = (int*)alloc((size_t)Ntot * 4);
  float* rd3    = (float*)alloc((size_t)Ntot * 4);
  f32x4* k4s    = (f32x4*)alloc((size_t)Mtot * 16);
  f32x4* u4s    = (f32x4*)alloc((size_t)Ntot * 16);
  float* wgt    = (float*)alloc((size_t)Ntot * 3 * 4);
  int*   idx    = (int*)alloc((size_t)Ntot * 3 * 4);
  __hip_bfloat16* y1b = (__hip_bfloat16*)alloc((size_t)Ntot * 128 * 2);
  __hip_bfloat16* y2b = (__hip_bfloat16*)alloc((size_t)Ntot * 128 * 2);
  __hip_bfloat16* Wb1 = (__hip_bfloat16*)alloc(128 * 128 * 2);
  __hip_bfloat16* Wb2 = (__hip_bfloat16*)alloc(128 * 128 * 2);

  float* y2 = (float*)d_out;
  long n8 = (long)Ntot * 128 / 8;
  float invN = 1.0f / (float)Ntot;
  int nb = n2 / 1024;
  float* stats2 = stats + NREP * 256;
  int zn4 = (int)(zero_bytes / 16);

  zero_k<<<(zn4 + 255) / 256, 256, 0, stream>>>((int4*)stats, zn4);
  hist_k<<<(Ntot + 255) / 256, 256, 0, stream>>>(known, Mtot, Mi, unknown, Ntot,
                                                 khist, qhist, kcell, qcell, W1, W2, Wb1, Wb2);
  scan1_k<<<nb, 256, 0, stream>>>((const int4*)khist, bsum);
  scan3_k<<<nb, 256, 0, stream>>>((const int4*)khist, bsum, nb, kstart, kfill,
                                  qstart, qfill, nc, Mtot, Ntot);
  scatter_k<<<(Ntot + 255) / 256, 256, 0, stream>>>(known, Mtot, Mi, unknown, Ntot,
                                                    kcell, qcell, kfill, qfill, k4s, korder, u4s, qorder);
  knn_grid_k<<<Ntot / 32, 256, 0, stream>>>(u4s, qorder, kstart, k4s, korder, Ni,
                                            wgt, idx, rcnt, rlist, rd3);
  knn_retry_k<<<1024, 256, 0, stream>>>(u4s, qorder, rlist, rd3, rcnt,
                                        kstart, k4s, korder, Ni, wgt, idx);
  gemm1_fused_k<<<Ntot / 32, 256, 0, stream>>>(kf, uf, wgt, idx, Wb1, y1b, stats, Ni, Mi);
  gemm2_bn_k<<<Ntot / 32, 256, 0, stream>>>(y1b, stats, g1, b1, invN, Wb2, y2b, stats2);
  bnrelu_out_k<<<2048, 256, 0, stream>>>(y2b, stats2, g2, b2, invN, y2, n8);
}